// Round 1
// baseline (141.532 us; speedup 1.0000x reference)
//
#include <hip/hip_runtime.h>
#include <math.h>

#define N_STEPS 10240
#define BLOCK_N 512
#define HOPN 256
#define ROWF2 264          // float2 slots per spectral row (257 used, padded for 16B alignment)
#define ROWF  (ROWF2*2)    // floats per row = 528
#define ENV_N 327744       // N_FRAMES*32
#define LCH 64             // scan chunk length
#define KWARM 48           // warm-up steps (contraction 0.283^48 ~ 1e-26 -> exact in fp32)

// ---------------- shared-memory complex FFT-256, 256 threads ----------------
// dir = -1: forward (e^{-2pi i}), unnormalized.  dir = +1: inverse SUM (no 1/N).
__device__ inline void fft256(float2* s, int t, float dir) {
  __syncthreads();                       // caller just wrote s[t]
  unsigned rb = __brev((unsigned)t) >> 24;
  float2 v = s[rb];
  __syncthreads();
  s[t] = v;
  __syncthreads();
  #pragma unroll
  for (int st = 1; st <= 8; ++st) {
    const int half = 1 << (st - 1);
    const int m = half << 1;
    int pos = t & (half - 1);
    float ang = dir * 6.283185307179586f * ((float)pos / (float)m);
    float sn, c;
    sincosf(ang, &sn, &c);
    bool up = (t & half) != 0;
    float2 mine = s[t];
    float2 other = s[up ? (t - half) : (t + half)];
    __syncthreads();
    float2 r;
    if (!up) {   // lower output: a + w*b
      r.x = mine.x + (c * other.x - sn * other.y);
      r.y = mine.y + (c * other.y + sn * other.x);
    } else {     // upper output: a - w*b  (other = lower input, mine = upper input)
      r.x = other.x - (c * mine.x - sn * mine.y);
      r.y = other.y - (c * mine.y + sn * mine.x);
    }
    s[t] = r;
    __syncthreads();
  }
}

// ---------------- kernel A: impulse spectra  IMP_j = drop(rfft_ortho(noise*exc) * etf) ----
__global__ __launch_bounds__(256) void kernA(const float* __restrict__ env,
                                             const float* __restrict__ noise,
                                             const float* __restrict__ etf_re,
                                             const float* __restrict__ etf_im,
                                             float* __restrict__ IMP) {
  const int j = blockIdx.x;
  const int t = threadIdx.x;
  float* rowf = IMP + (size_t)j * ROWF;
  if (j == N_STEPS) {                    // IMP row N_STEPS = 0 (last step adds nothing)
    for (int k = t; k < ROWF; k += 256) rowf[k] = 0.f;
    return;
  }
  __shared__ float2 z[256];
  float w0 = 0.f, w1 = 0.f;
  {
    const int g = HOPN * j + 2 * t;
    #pragma unroll
    for (int u = 0; u < 2; ++u) {
      float coords = ((float)(g + u) + 0.5f) * 0.125f - 0.5f;   // upsample x8, align_corners=False
      coords = fminf(fmaxf(coords, 0.f), (float)(ENV_N - 1));
      int lo = (int)coords;              // coords >= 0 -> trunc == floor
      int hi = min(lo + 1, ENV_N - 1);
      float fr = coords - (float)lo;
      float e0 = env[lo]; e0 *= e0;      // env squared, then interpolated (matches ref)
      float e1 = env[hi]; e1 *= e1;
      float e = e0 * (1.f - fr) + e1 * fr;
      float wv = noise[(size_t)j * BLOCK_N + 2 * t + u] * e;
      if (u == 0) w0 = wv; else w1 = wv;
    }
  }
  z[t] = make_float2(w0, w1);            // pack even/odd real samples as complex
  fft256(z, t, -1.0f);
  float2 Zk = z[t];
  float2 Zm = z[(256 - t) & 255];
  // untangle real-FFT: W_k = E_k + e^{-i pi k/256} O_k
  float Ex = 0.5f * (Zk.x + Zm.x), Ey = 0.5f * (Zk.y - Zm.y);
  float Dx = Zk.x - Zm.x,          Dy = Zk.y + Zm.y;
  float Ox = 0.5f * Dy,            Oy = -0.5f * Dx;         // D / (2i)
  float ang = -3.14159265358979f * (float)t / 256.0f;
  float sn, c; sincosf(ang, &sn, &c);
  const float FS = 0.04419417382415922f; // 1/sqrt(512) (ortho)
  float Wx = (Ex + (c * Ox - sn * Oy)) * FS;
  float Wy = (Ey + (c * Oy + sn * Ox)) * FS;
  float er = etf_re[t], ei = etf_im[t];
  float Px = Wx * er - Wy * ei;
  float Py = Wx * ei + Wy * er;
  if (t == 0) Py = 0.f;                  // irfft drops Im at DC
  float2* row = (float2*)rowf;
  row[t] = make_float2(Px, Py);
  if (t == 0) {                          // Nyquist bin (real)
    float W256 = (Zk.x - Zk.y) * FS;     // Zk == Z0 here
    row[256] = make_float2(W256 * etf_re[256], 0.f);
  }
}

// ---------------- kernel B: chunked frequency-domain scan ----------------
// S_{i+1} = conv3( drop( tf_i . S_i ) ) + IMP_{i+1},   conv3 = [-0.23, 0.54, -0.23]
struct StepBuf {
  float tr0, tr1, tr2, tr3;
  float ti0, ti1, ti2, ti3;
  float tf256r;
  float4 ia, ib;
  float i256;
};

__device__ inline void loadStep(StepBuf& b, int i, int l,
                                const float* __restrict__ tf_re,
                                const float* __restrict__ tf_im,
                                const float* __restrict__ IMP) {
  size_t tb = (size_t)i * 257 + 4 * l;
  b.tr0 = tf_re[tb]; b.tr1 = tf_re[tb + 1]; b.tr2 = tf_re[tb + 2]; b.tr3 = tf_re[tb + 3];
  b.ti0 = tf_im[tb]; b.ti1 = tf_im[tb + 1]; b.ti2 = tf_im[tb + 2]; b.ti3 = tf_im[tb + 3];
  b.tf256r = tf_re[(size_t)i * 257 + 256];
  const float4* r4 = (const float4*)(IMP + (size_t)(i + 1) * ROWF);
  b.ia = r4[2 * l];
  b.ib = r4[2 * l + 1];
  b.i256 = IMP[(size_t)(i + 1) * ROWF + 512];
}

__device__ inline void doStep(int i, int j0, const StepBuf& b, int l,
                              float2& s0, float2& s1, float2& s2, float2& s3,
                              float& s256, float* __restrict__ S) {
  float2 y0, y1, y2, y3;
  y0.x = s0.x * b.tr0 - s0.y * b.ti0;  y0.y = s0.x * b.ti0 + s0.y * b.tr0;
  y1.x = s1.x * b.tr1 - s1.y * b.ti1;  y1.y = s1.x * b.ti1 + s1.y * b.tr1;
  y2.x = s2.x * b.tr2 - s2.y * b.ti2;  y2.y = s2.x * b.ti2 + s2.y * b.tr2;
  y3.x = s3.x * b.tr3 - s3.y * b.ti3;  y3.y = s3.x * b.ti3 + s3.y * b.tr3;
  if (l == 0) y0.y = 0.f;              // drop Im at DC (irfft semantics)
  float Y256 = b.tf256r * s256;        // Nyquist, real (Im dropped)
  // neighbor bins across lanes
  float phx = __shfl_up(y3.x, 1), phy = __shfl_up(y3.y, 1);
  float nlx = __shfl_down(y0.x, 1), nly = __shfl_down(y0.y, 1);
  float2 p0 = (l == 0)  ? make_float2(y1.x, -y1.y) : make_float2(phx, phy);  // Y_{-1} = conj(Y_1)
  float2 n3 = (l == 63) ? make_float2(Y256, 0.f)   : make_float2(nlx, nly);  // Y_256 (real)
  float y255x = __shfl(y3.x, 63);      // Re(Y_255) for Nyquist update
  const float A = 0.54f, Bc = 0.23f;
  float2 c0, c1, c2, c3;
  c0.x = A * y0.x - Bc * (p0.x + y1.x);  c0.y = A * y0.y - Bc * (p0.y + y1.y);
  c1.x = A * y1.x - Bc * (y0.x + y2.x);  c1.y = A * y1.y - Bc * (y0.y + y2.y);
  c2.x = A * y2.x - Bc * (y1.x + y3.x);  c2.y = A * y2.y - Bc * (y1.y + y3.y);
  c3.x = A * y3.x - Bc * (y2.x + n3.x);  c3.y = A * y3.y - Bc * (y2.y + n3.y);
  float C256 = A * Y256 - 0.46f * y255x;
  s0.x = c0.x + b.ia.x;  s0.y = c0.y + b.ia.y;
  s1.x = c1.x + b.ia.z;  s1.y = c1.y + b.ia.w;
  s2.x = c2.x + b.ib.x;  s2.y = c2.y + b.ib.y;
  s3.x = c3.x + b.ib.z;  s3.y = c3.y + b.ib.w;
  s256 = C256 + b.i256;
  if (i >= j0) {                       // store S_{i+1} (warm-up steps are not stored)
    float4* o4 = (float4*)(S + (size_t)(i + 1) * ROWF);
    o4[2 * l]     = make_float4(s0.x, s0.y, s1.x, s1.y);
    o4[2 * l + 1] = make_float4(s2.x, s2.y, s3.x, s3.y);
    if (l == 0) {
      S[(size_t)(i + 1) * ROWF + 512] = s256;
      S[(size_t)(i + 1) * ROWF + 513] = 0.f;
    }
  }
}

__global__ __launch_bounds__(64) void kernB(const float* __restrict__ tf_re,
                                            const float* __restrict__ tf_im,
                                            const float* __restrict__ IMP,
                                            float* __restrict__ S) {
  const int c = blockIdx.x, l = threadIdx.x;
  const int j0 = c * LCH;
  const int jend = min(j0 + LCH, N_STEPS);
  const int w0 = max(0, j0 - KWARM);
  float2 s0 = make_float2(0.f, 0.f), s1 = s0, s2 = s0, s3 = s0;
  float s256 = 0.f;
  if (c == 0) {                        // exact init: S_0 = IMP_0; also store row 0
    const float4* r4 = (const float4*)IMP;
    float4 a = r4[2 * l], bb = r4[2 * l + 1];
    s0 = make_float2(a.x, a.y);  s1 = make_float2(a.z, a.w);
    s2 = make_float2(bb.x, bb.y); s3 = make_float2(bb.z, bb.w);
    s256 = IMP[512];
    float4* o4 = (float4*)S;
    o4[2 * l] = a; o4[2 * l + 1] = bb;
    if (l == 0) { S[512] = s256; S[513] = 0.f; }
  }
  StepBuf A_, B_;
  loadStep(A_, w0, l, tf_re, tf_im, IMP);
  int i = w0;
  while (i < jend) {                   // depth-2 software pipeline
    loadStep(B_, min(i + 1, jend - 1), l, tf_re, tf_im, IMP);
    doStep(i, j0, A_, l, s0, s1, s2, s3, s256, S);
    ++i;
    if (i >= jend) break;
    loadStep(A_, min(i + 1, jend - 1), l, tf_re, tf_im, IMP);
    doStep(i, j0, B_, l, s0, s1, s2, s3, s256, S);
    ++i;
  }
}

// ---------------- kernel C: irfft blocks + overlap-add gather ----------------
__global__ __launch_bounds__(256) void kernC(const float* __restrict__ S,
                                             float* __restrict__ out) {
  const int q = blockIdx.x, t = threadIdx.x;
  __shared__ float2 spec[257];
  __shared__ float2 z[256];
  __shared__ float ybuf[2][512];
  const float ISC = 0.08838834764831845f;   // sqrt(512)/256 (ortho inverse via unnormalized sum)
  for (int pass = 0; pass < 2; ++pass) {
    if (pass == 1 && q == 0) break;          // block-uniform
    const int b = (pass == 0) ? q : (q - 1);
    const float2* row = (const float2*)(S + (size_t)b * ROWF);
    spec[t] = row[t];
    if (t == 0) spec[256] = row[256];
    __syncthreads();
    float2 Wk = spec[t], Wm = spec[256 - t];
    float Ex = 0.5f * (Wk.x + Wm.x), Ey = 0.5f * (Wk.y - Wm.y);
    float Dx = Wk.x - Wm.x,          Dy = Wk.y + Wm.y;
    float ang = 3.14159265358979f * (float)t / 256.0f;
    float sn, c; sincosf(ang, &sn, &c);
    float Ox = 0.5f * (c * Dx - sn * Dy);
    float Oy = 0.5f * (c * Dy + sn * Dx);
    z[t] = make_float2(Ex - Oy, Ey + Ox);    // Z_k = E_k + i O_k
    fft256(z, t, +1.0f);
    float2 v = z[t];
    ybuf[pass][2 * t]     = v.x * ISC;
    ybuf[pass][2 * t + 1] = v.y * ISC;
    __syncthreads();
  }
  float o = ybuf[0][t] + ((q > 0) ? ybuf[1][t + 256] : 0.f);
  out[(size_t)q * HOPN + t] = o;
}

// ---------------- launch ----------------
extern "C" void kernel_launch(void* const* d_in, const int* in_sizes, int n_in,
                              void* d_out, int out_size, void* d_ws, size_t ws_size,
                              hipStream_t stream) {
  const float* env    = (const float*)d_in[1];
  const float* tf_re  = (const float*)d_in[2];
  const float* tf_im  = (const float*)d_in[3];
  const float* etf_re = (const float*)d_in[4];
  const float* etf_im = (const float*)d_in[5];
  const float* noise  = (const float*)d_in[6];
  float* out = (float*)d_out;

  float* wsf = (float*)d_ws;
  float* IMP = wsf;                                        // (N_STEPS+1) x ROWF floats
  float* S   = wsf + (size_t)(N_STEPS + 1) * ROWF;         // (N_STEPS+1) x ROWF floats
  // total ws use: 2 * 10241 * 528 * 4 B ~= 43.3 MB

  kernA<<<N_STEPS + 1, 256, 0, stream>>>(env, noise, etf_re, etf_im, IMP);
  kernB<<<(N_STEPS + LCH - 1) / LCH, 64, 0, stream>>>(tf_re, tf_im, IMP, S);
  kernC<<<N_STEPS, 256, 0, stream>>>(S, out);
}

// Round 2
// 65.990 us; speedup vs baseline: 2.1447x; 2.1447x over previous
//
#include <hip/hip_runtime.h>
#include <math.h>

#define N_STEPS 10240
#define ROWF2 264          // float2 slots per spectral row (257 used, padded)
#define ROWF  (ROWF2*2)    // floats per row = 528
#define ENV_N 327744       // N_FRAMES*32
#define LCH 64             // scan chunk length
#define KWARM 24           // warm-up steps (contraction 0.283^24 ~ 7e-14)

typedef float f4a __attribute__((ext_vector_type(4), aligned(4)));

__device__ inline float2 mkf2(float x, float y) { return make_float2(x, y); }

// ---------------- wave-level complex FFT-256: 64 lanes, 4 float2 regs -------
// Input:  v[r] = x[4*l + r]   (lane l, natural order)
// Output: v[k1] = X[64*k1 + l]
// DIR = -1 forward (e^{-2pi i}), +1 inverse SUM (no 1/N). No LDS, no barriers.
template<int DIR>
__device__ inline void waveFFT256(float2 v[4], const int l) {
  // (a) bit-reverse lanes for cross-lane DIT
  const int rb = (int)(__brev((unsigned)l) >> 26);
  #pragma unroll
  for (int r = 0; r < 4; ++r) {
    v[r].x = __shfl(v[r].x, rb);
    v[r].y = __shfl(v[r].y, rb);
  }
  // (b) 6 cross-lane radix-2 DIT stages, uniform butterfly:
  //     w'(l) = e^{DIR*2pi i*(l*2^{5-s} mod 64)/64}; v = sel(a) + w' * sel(b)
  #pragma unroll
  for (int s = 0; s < 6; ++s) {
    const int half = 1 << s;
    float wx, wy;
    if (s == 0) { wx = (l & 1) ? -1.f : 1.f; wy = 0.f; }
    else {
      float ang = (float)DIR * 0.09817477042468103f * (float)((l << (5 - s)) & 63); // 2pi/64
      sincosf(ang, &wy, &wx);
    }
    #pragma unroll
    for (int r = 0; r < 4; ++r) {
      float tx = __shfl_xor(v[r].x, half);
      float ty = __shfl_xor(v[r].y, half);
      const bool low = (l & half) == 0;
      float ax = low ? v[r].x : tx, ay = low ? v[r].y : ty;
      float bx = low ? tx : v[r].x, by = low ? ty : v[r].y;
      v[r].x = ax + (wx * bx - wy * by);
      v[r].y = ay + (wx * by + wy * bx);
    }
  }
  // (c) per-reg twiddle u^r, u = e^{DIR*2pi i l/256}
  float ux, uy;
  { float ang = (float)DIR * 0.02454369260617026f * (float)l; sincosf(ang, &uy, &ux); }
  const float u2x = ux * ux - uy * uy, u2y = 2.f * ux * uy;
  const float u3x = u2x * ux - u2y * uy, u3y = u2x * uy + u2y * ux;
  float2 t0 = v[0];
  float2 t1 = mkf2(v[1].x * ux - v[1].y * uy, v[1].x * uy + v[1].y * ux);
  float2 t2 = mkf2(v[2].x * u2x - v[2].y * u2y, v[2].x * u2y + v[2].y * u2x);
  float2 t3 = mkf2(v[3].x * u3x - v[3].y * u3y, v[3].x * u3y + v[3].y * u3x);
  // (d) radix-4 across regs
  float2 p02 = mkf2(t0.x + t2.x, t0.y + t2.y), m02 = mkf2(t0.x - t2.x, t0.y - t2.y);
  float2 p13 = mkf2(t1.x + t3.x, t1.y + t3.y), m13 = mkf2(t1.x - t3.x, t1.y - t3.y);
  v[0] = mkf2(p02.x + p13.x, p02.y + p13.y);
  v[2] = mkf2(p02.x - p13.x, p02.y - p13.y);
  if (DIR < 0) {
    v[1] = mkf2(m02.x + m13.y, m02.y - m13.x);   // m02 - i*m13
    v[3] = mkf2(m02.x - m13.y, m02.y + m13.x);   // m02 + i*m13
  } else {
    v[1] = mkf2(m02.x - m13.y, m02.y + m13.x);
    v[3] = mkf2(m02.x + m13.y, m02.y - m13.x);
  }
}

// ---------------- kernel A: impulse spectra (one wave per step j) -----------
__global__ __launch_bounds__(256) void kernA(const float* __restrict__ env,
                                             const float* __restrict__ noise,
                                             const float* __restrict__ etf_re,
                                             const float* __restrict__ etf_im,
                                             float* __restrict__ IMP) {
  const int l = threadIdx.x & 63;
  const int j = blockIdx.x * 4 + (threadIdx.x >> 6);
  float* rowf = IMP + (size_t)j * ROWF;
  float2* row = (float2*)rowf;
  if (j >= N_STEPS) {
    if (j == N_STEPS) {                  // row N_STEPS = 0 (read by kernB's tail prefetch)
      #pragma unroll
      for (int r = 0; r < 4; ++r) row[64 * r + l] = mkf2(0.f, 0.f);
      if (l == 0) row[256] = mkf2(0.f, 0.f);
    }
    return;
  }
  // excitation: coords = 32j + l + (u-3.5)/8  ->  only env[K-1], env[K], env[K+1]
  const int K = 32 * j + l;
  float e0 = env[K];                e0 *= e0;
  float em = env[max(K - 1, 0)];    em *= em;
  float ep = env[min(K + 1, ENV_N - 1)]; ep *= ep;
  float sm[8];
  #pragma unroll
  for (int u = 0; u < 8; ++u) {
    float val;
    if (u < 4) {
      float fr = 0.5625f + 0.125f * (float)u;
      val = em * (1.f - fr) + e0 * fr;
      if (K == 0) val = e0;              // ref clamps coords at 0
    } else {
      float fr = 0.0625f + 0.125f * (float)(u - 4);
      val = e0 * (1.f - fr) + ep * fr;
    }
    sm[u] = val;
  }
  const float4* np = (const float4*)(noise + (size_t)j * 512 + 8 * l);
  float4 n0 = np[0], n1 = np[1];
  float nn[8] = {n0.x, n0.y, n0.z, n0.w, n1.x, n1.y, n1.z, n1.w};
  float2 v[4];
  #pragma unroll
  for (int r = 0; r < 4; ++r)
    v[r] = mkf2(nn[2 * r] * sm[2 * r], nn[2 * r + 1] * sm[2 * r + 1]);

  waveFFT256<-1>(v, l);                  // v[r] = Z[64r + l]

  // real-FFT untangle: need conj(Z[(256-k) mod 256]); k = 64r+l
  float2 Zc[4];
  const int pidx = (64 - l) & 63;
  #pragma unroll
  for (int r = 0; r < 4; ++r) {
    Zc[r].x = __shfl(v[3 - r].x, pidx);
    Zc[r].y = __shfl(v[3 - r].y, pidx);
  }
  float2 z0lane = v[0];                  // Z_0 on lane 0 (for Nyquist)
  if (l == 0) { Zc[0] = v[0]; Zc[1] = v[3]; Zc[2] = v[2]; Zc[3] = v[1]; }
  float cl, sl_;
  sincosf(-0.01227184630308513f * (float)l, &sl_, &cl);   // e^{-i pi l/256}
  constexpr float crA[4] = {1.f, 0.7071067811865476f, 0.f, -0.7071067811865476f};
  constexpr float srA[4] = {0.f, -0.7071067811865476f, -1.f, -0.7071067811865476f};
  const float FS = 0.04419417382415922f;                  // 1/sqrt(512)
  #pragma unroll
  for (int r = 0; r < 4; ++r) {
    float Ex = 0.5f * (v[r].x + Zc[r].x), Ey = 0.5f * (v[r].y - Zc[r].y);
    float Dx = v[r].x - Zc[r].x,          Dy = v[r].y + Zc[r].y;
    float Ox = 0.5f * Dy, Oy = -0.5f * Dx;
    float c  = crA[r] * cl - srA[r] * sl_;                // e^{-i pi k/256}
    float sn = crA[r] * sl_ + srA[r] * cl;
    float Wx = (Ex + (c * Ox - sn * Oy)) * FS;
    float Wy = (Ey + (c * Oy + sn * Ox)) * FS;
    int k = 64 * r + l;
    float er = etf_re[k], ei = etf_im[k];
    float Px = Wx * er - Wy * ei;
    float Py = Wx * ei + Wy * er;
    if (k == 0) Py = 0.f;                // irfft drops Im at DC
    row[k] = mkf2(Px, Py);
  }
  if (l == 0) {
    float W256 = (z0lane.x - z0lane.y) * FS;
    row[256] = mkf2(W256 * etf_re[256], 0.f);
  }
}

// ---------------- kernel B: chunked frequency-domain scan, 8-deep pipeline --
struct StepBuf {
  f4a tr, ti;
  float tf256r;
  float4 ia, ib;
  float i256;
};

__device__ inline void loadStep(StepBuf& b, int i, int l,
                                const float* __restrict__ tf_re,
                                const float* __restrict__ tf_im,
                                const float* __restrict__ IMP) {
  const size_t tb = (size_t)i * 257 + 4 * l;
  b.tr = *(const f4a*)(tf_re + tb);
  b.ti = *(const f4a*)(tf_im + tb);
  b.tf256r = tf_re[(size_t)i * 257 + 256];
  const float4* r4 = (const float4*)(IMP + (size_t)(i + 1) * ROWF);
  b.ia = r4[2 * l];
  b.ib = r4[2 * l + 1];
  b.i256 = IMP[(size_t)(i + 1) * ROWF + 512];
}

__device__ inline void doStep(int i, int j0, const StepBuf& b, int l,
                              float2& s0, float2& s1, float2& s2, float2& s3,
                              float& s256, float* __restrict__ S) {
  float2 y0, y1, y2, y3;
  y0.x = s0.x * b.tr[0] - s0.y * b.ti[0];  y0.y = s0.x * b.ti[0] + s0.y * b.tr[0];
  y1.x = s1.x * b.tr[1] - s1.y * b.ti[1];  y1.y = s1.x * b.ti[1] + s1.y * b.tr[1];
  y2.x = s2.x * b.tr[2] - s2.y * b.ti[2];  y2.y = s2.x * b.ti[2] + s2.y * b.tr[2];
  y3.x = s3.x * b.tr[3] - s3.y * b.ti[3];  y3.y = s3.x * b.ti[3] + s3.y * b.tr[3];
  if (l == 0) y0.y = 0.f;              // drop Im at DC (irfft semantics)
  float Y256 = b.tf256r * s256;        // Nyquist, real (Im dropped)
  float phx = __shfl_up(y3.x, 1), phy = __shfl_up(y3.y, 1);
  float nlx = __shfl_down(y0.x, 1), nly = __shfl_down(y0.y, 1);
  float2 p0 = (l == 0)  ? mkf2(y1.x, -y1.y) : mkf2(phx, phy);  // Y_{-1} = conj(Y_1)
  float2 n3 = (l == 63) ? mkf2(Y256, 0.f)   : mkf2(nlx, nly);  // Y_256 (real)
  float y255x = __shfl(y3.x, 63);
  const float A = 0.54f, Bc = 0.23f;
  float2 c0, c1, c2, c3;
  c0.x = A * y0.x - Bc * (p0.x + y1.x);  c0.y = A * y0.y - Bc * (p0.y + y1.y);
  c1.x = A * y1.x - Bc * (y0.x + y2.x);  c1.y = A * y1.y - Bc * (y0.y + y2.y);
  c2.x = A * y2.x - Bc * (y1.x + y3.x);  c2.y = A * y2.y - Bc * (y1.y + y3.y);
  c3.x = A * y3.x - Bc * (y2.x + n3.x);  c3.y = A * y3.y - Bc * (y2.y + n3.y);
  float C256 = A * Y256 - 0.46f * y255x;
  s0.x = c0.x + b.ia.x;  s0.y = c0.y + b.ia.y;
  s1.x = c1.x + b.ia.z;  s1.y = c1.y + b.ia.w;
  s2.x = c2.x + b.ib.x;  s2.y = c2.y + b.ib.y;
  s3.x = c3.x + b.ib.z;  s3.y = c3.y + b.ib.w;
  s256 = C256 + b.i256;
  if (i >= j0) {
    float4* o4 = (float4*)(S + (size_t)(i + 1) * ROWF);
    o4[2 * l]     = make_float4(s0.x, s0.y, s1.x, s1.y);
    o4[2 * l + 1] = make_float4(s2.x, s2.y, s3.x, s3.y);
    if (l == 0) {
      S[(size_t)(i + 1) * ROWF + 512] = s256;
      S[(size_t)(i + 1) * ROWF + 513] = 0.f;
    }
  }
}

__global__ __launch_bounds__(64) void kernB(const float* __restrict__ tf_re,
                                            const float* __restrict__ tf_im,
                                            const float* __restrict__ IMP,
                                            float* __restrict__ S) {
  const int c = blockIdx.x, l = threadIdx.x;
  const int j0 = c * LCH;
  const int jend = min(j0 + LCH, N_STEPS);
  const int w0 = max(0, j0 - KWARM);     // nsteps = 64 (c==0) or 88 -> both %8==0
  const int last = jend - 1;
  float2 s0 = mkf2(0.f, 0.f), s1 = s0, s2 = s0, s3 = s0;
  float s256 = 0.f;
  if (c == 0) {                          // exact init: S_0 = IMP_0; store row 0
    const float4* r4 = (const float4*)IMP;
    float4 a = r4[2 * l], bb = r4[2 * l + 1];
    s0 = mkf2(a.x, a.y);  s1 = mkf2(a.z, a.w);
    s2 = mkf2(bb.x, bb.y); s3 = mkf2(bb.z, bb.w);
    s256 = IMP[512];
    float4* o4 = (float4*)S;
    o4[2 * l] = a; o4[2 * l + 1] = bb;
    if (l == 0) { S[512] = s256; S[513] = 0.f; }
  }
  StepBuf b0, b1, b2, b3, b4, b5, b6, b7;
  loadStep(b0, w0 + 0, l, tf_re, tf_im, IMP);
  loadStep(b1, w0 + 1, l, tf_re, tf_im, IMP);
  loadStep(b2, w0 + 2, l, tf_re, tf_im, IMP);
  loadStep(b3, w0 + 3, l, tf_re, tf_im, IMP);
  loadStep(b4, w0 + 4, l, tf_re, tf_im, IMP);
  loadStep(b5, w0 + 5, l, tf_re, tf_im, IMP);
  loadStep(b6, w0 + 6, l, tf_re, tf_im, IMP);
  loadStep(b7, w0 + 7, l, tf_re, tf_im, IMP);
  int i = w0;
  #define STEP8(BUF) \
    doStep(i, j0, BUF, l, s0, s1, s2, s3, s256, S); \
    { int nx = i + 8; nx = (nx > last) ? last : nx; loadStep(BUF, nx, l, tf_re, tf_im, IMP); } \
    ++i;
  while (i < jend) {
    STEP8(b0) STEP8(b1) STEP8(b2) STEP8(b3)
    STEP8(b4) STEP8(b5) STEP8(b6) STEP8(b7)
  }
  #undef STEP8
}

// ---------------- kernel C1: irfft each block row once (one wave per row) ---
__global__ __launch_bounds__(256) void kernC1(const float* __restrict__ S,
                                              float* __restrict__ Y) {
  const int l = threadIdx.x & 63;
  const int b = blockIdx.x * 4 + (threadIdx.x >> 6);   // b < N_STEPS
  const float2* row = (const float2*)(S + (size_t)b * ROWF);
  const float4* r4 = (const float4*)row;
  float4 a = r4[2 * l], bb = r4[2 * l + 1];
  float2 W[4] = {mkf2(a.x, a.y), mkf2(a.z, a.w), mkf2(bb.x, bb.y), mkf2(bb.z, bb.w)};
  float w256 = row[256].x;
  // partner W[256-k], k = 4l+r
  float2 Wm[4];
  const int pidx = (64 - l) & 63;
  Wm[0].x = __shfl(W[0].x, pidx);
  Wm[0].y = __shfl(W[0].y, pidx);
  if (l == 0) Wm[0] = mkf2(w256, 0.f);
  Wm[1].x = __shfl_xor(W[3].x, 63);  Wm[1].y = __shfl_xor(W[3].y, 63);
  Wm[2].x = __shfl_xor(W[2].x, 63);  Wm[2].y = __shfl_xor(W[2].y, 63);
  Wm[3].x = __shfl_xor(W[1].x, 63);  Wm[3].y = __shfl_xor(W[1].y, 63);
  // pack: Z_k = E_k + i O_k, twiddle e^{+i pi k/256} = e^{+i pi l/64} * e^{+i pi r/256}
  float cl, sl_;
  sincosf(0.04908738521234052f * (float)l, &sl_, &cl);
  constexpr float crC[4] = {1.f, 0.9999247018391445f, 0.9996988186962042f, 0.9993223845883495f};
  constexpr float srC[4] = {0.f, 0.0122715382857199f, 0.0245412285229123f, 0.0368072229413588f};
  float2 v[4];
  #pragma unroll
  for (int r = 0; r < 4; ++r) {
    float Ex = 0.5f * (W[r].x + Wm[r].x), Ey = 0.5f * (W[r].y - Wm[r].y);
    float Dx = W[r].x - Wm[r].x,          Dy = W[r].y + Wm[r].y;
    float c  = cl * crC[r] - sl_ * srC[r];
    float sn = cl * srC[r] + sl_ * crC[r];
    float Ox = 0.5f * (c * Dx - sn * Dy);
    float Oy = 0.5f * (c * Dy + sn * Dx);
    v[r] = mkf2(Ex - Oy, Ey + Ox);
  }
  waveFFT256<+1>(v, l);                  // v[k1] = z[64*k1 + l]
  const float ISC = 0.08838834764831845f;  // sqrt(512)/256
  float2* yrow = (float2*)(Y + (size_t)b * 512);
  #pragma unroll
  for (int r = 0; r < 4; ++r)
    yrow[64 * r + l] = mkf2(v[r].x * ISC, v[r].y * ISC);  // y[2n], y[2n+1], n = 64r+l
}

// ---------------- kernel C2: overlap-add (each Y element read exactly once) -
__global__ __launch_bounds__(256) void kernC2(const float* __restrict__ Y,
                                              float* __restrict__ out) {
  const int gid = blockIdx.x * 256 + threadIdx.x;      // < 655360
  const int q = gid >> 6;
  const int t4 = gid & 63;
  const float4* yq = (const float4*)(Y + (size_t)q * 512);
  float4 a = yq[t4];
  if (q > 0) {
    const float4* yp = (const float4*)(Y + (size_t)(q - 1) * 512);
    float4 bl = yp[64 + t4];
    a.x += bl.x; a.y += bl.y; a.z += bl.z; a.w += bl.w;
  }
  ((float4*)out)[gid] = a;
}

// ---------------- launch ----------------
extern "C" void kernel_launch(void* const* d_in, const int* in_sizes, int n_in,
                              void* d_out, int out_size, void* d_ws, size_t ws_size,
                              hipStream_t stream) {
  const float* env    = (const float*)d_in[1];
  const float* tf_re  = (const float*)d_in[2];
  const float* tf_im  = (const float*)d_in[3];
  const float* etf_re = (const float*)d_in[4];
  const float* etf_im = (const float*)d_in[5];
  const float* noise  = (const float*)d_in[6];
  float* out = (float*)d_out;

  float* wsf = (float*)d_ws;
  float* IMP = wsf;                                    // (N_STEPS+1) x ROWF
  float* S   = wsf + (size_t)(N_STEPS + 1) * ROWF;     // (N_STEPS+1) x ROWF
  float* Y   = wsf;                                    // alias IMP (dead after kernB)
  // ws use: 2 * 10241 * 528 * 4 B ~= 43.3 MB

  kernA<<<(N_STEPS / 4) + 1, 256, 0, stream>>>(env, noise, etf_re, etf_im, IMP);
  kernB<<<N_STEPS / LCH, 64, 0, stream>>>(tf_re, tf_im, IMP, S);
  kernC1<<<N_STEPS / 4, 256, 0, stream>>>(S, Y);
  kernC2<<<N_STEPS * 64 / 256, 256, 0, stream>>>(Y, out);
}

// Round 3
// 60.950 us; speedup vs baseline: 2.3221x; 1.0827x over previous
//
#include <hip/hip_runtime.h>
#include <math.h>

#define N_STEPS 10240
#define ROWF2 264          // float2 slots per spectral row (257 used, padded)
#define ROWF  (ROWF2*2)    // floats per row = 528
#define ENV_N 327744       // N_FRAMES*32
#define LCH 32             // scan chunk length
#define KWARM 16           // warm-up steps (contraction 0.283^16 ~ 1.6e-9 rel)

typedef float f4a __attribute__((ext_vector_type(4), aligned(4)));

__device__ inline float2 mkf2(float x, float y) { return make_float2(x, y); }

// ---------------- wave-level complex FFT-256: 64 lanes, 4 float2 regs -------
// Input:  v[r] = x[4*l + r]   (lane l, natural order)
// Output: v[k1] = X[64*k1 + l]
// DIR = -1 forward (e^{-2pi i}), +1 inverse SUM (no 1/N). No LDS, no barriers.
template<int DIR>
__device__ inline void waveFFT256(float2 v[4], const int l) {
  // (a) bit-reverse lanes for cross-lane DIT
  const int rb = (int)(__brev((unsigned)l) >> 26);
  #pragma unroll
  for (int r = 0; r < 4; ++r) {
    v[r].x = __shfl(v[r].x, rb);
    v[r].y = __shfl(v[r].y, rb);
  }
  // (b) 6 cross-lane radix-2 DIT stages, uniform butterfly
  #pragma unroll
  for (int s = 0; s < 6; ++s) {
    const int half = 1 << s;
    float wx, wy;
    if (s == 0) { wx = (l & 1) ? -1.f : 1.f; wy = 0.f; }
    else {
      float ang = (float)DIR * 0.09817477042468103f * (float)((l << (5 - s)) & 63); // 2pi/64
      sincosf(ang, &wy, &wx);
    }
    #pragma unroll
    for (int r = 0; r < 4; ++r) {
      float tx = __shfl_xor(v[r].x, half);
      float ty = __shfl_xor(v[r].y, half);
      const bool low = (l & half) == 0;
      float ax = low ? v[r].x : tx, ay = low ? v[r].y : ty;
      float bx = low ? tx : v[r].x, by = low ? ty : v[r].y;
      v[r].x = ax + (wx * bx - wy * by);
      v[r].y = ay + (wx * by + wy * bx);
    }
  }
  // (c) per-reg twiddle u^r, u = e^{DIR*2pi i l/256}
  float ux, uy;
  { float ang = (float)DIR * 0.02454369260617026f * (float)l; sincosf(ang, &uy, &ux); }
  const float u2x = ux * ux - uy * uy, u2y = 2.f * ux * uy;
  const float u3x = u2x * ux - u2y * uy, u3y = u2x * uy + u2y * ux;
  float2 t0 = v[0];
  float2 t1 = mkf2(v[1].x * ux - v[1].y * uy, v[1].x * uy + v[1].y * ux);
  float2 t2 = mkf2(v[2].x * u2x - v[2].y * u2y, v[2].x * u2y + v[2].y * u2x);
  float2 t3 = mkf2(v[3].x * u3x - v[3].y * u3y, v[3].x * u3y + v[3].y * u3x);
  // (d) radix-4 across regs
  float2 p02 = mkf2(t0.x + t2.x, t0.y + t2.y), m02 = mkf2(t0.x - t2.x, t0.y - t2.y);
  float2 p13 = mkf2(t1.x + t3.x, t1.y + t3.y), m13 = mkf2(t1.x - t3.x, t1.y - t3.y);
  v[0] = mkf2(p02.x + p13.x, p02.y + p13.y);
  v[2] = mkf2(p02.x - p13.x, p02.y - p13.y);
  if (DIR < 0) {
    v[1] = mkf2(m02.x + m13.y, m02.y - m13.x);   // m02 - i*m13
    v[3] = mkf2(m02.x - m13.y, m02.y + m13.x);   // m02 + i*m13
  } else {
    v[1] = mkf2(m02.x - m13.y, m02.y + m13.x);
    v[3] = mkf2(m02.x + m13.y, m02.y - m13.x);
  }
}

// ---------------- kernel A: impulse spectra (one wave per step j) -----------
__global__ __launch_bounds__(256) void kernA(const float* __restrict__ env,
                                             const float* __restrict__ noise,
                                             const float* __restrict__ etf_re,
                                             const float* __restrict__ etf_im,
                                             float* __restrict__ IMP) {
  const int l = threadIdx.x & 63;
  const int j = blockIdx.x * 4 + (threadIdx.x >> 6);
  float* rowf = IMP + (size_t)j * ROWF;
  float2* row = (float2*)rowf;
  if (j >= N_STEPS) {
    if (j == N_STEPS) {                  // row N_STEPS = 0 (read by kernB's tail prefetch)
      #pragma unroll
      for (int r = 0; r < 4; ++r) row[64 * r + l] = mkf2(0.f, 0.f);
      if (l == 0) row[256] = mkf2(0.f, 0.f);
    }
    return;
  }
  const int K = 32 * j + l;
  float e0 = env[K];                e0 *= e0;
  float em = env[max(K - 1, 0)];    em *= em;
  float ep = env[min(K + 1, ENV_N - 1)]; ep *= ep;
  float sm[8];
  #pragma unroll
  for (int u = 0; u < 8; ++u) {
    float val;
    if (u < 4) {
      float fr = 0.5625f + 0.125f * (float)u;
      val = em * (1.f - fr) + e0 * fr;
      if (K == 0) val = e0;              // ref clamps coords at 0
    } else {
      float fr = 0.0625f + 0.125f * (float)(u - 4);
      val = e0 * (1.f - fr) + ep * fr;
    }
    sm[u] = val;
  }
  const float4* np = (const float4*)(noise + (size_t)j * 512 + 8 * l);
  float4 n0 = np[0], n1 = np[1];
  float nn[8] = {n0.x, n0.y, n0.z, n0.w, n1.x, n1.y, n1.z, n1.w};
  float2 v[4];
  #pragma unroll
  for (int r = 0; r < 4; ++r)
    v[r] = mkf2(nn[2 * r] * sm[2 * r], nn[2 * r + 1] * sm[2 * r + 1]);

  waveFFT256<-1>(v, l);                  // v[r] = Z[64r + l]

  float2 Zc[4];
  const int pidx = (64 - l) & 63;
  #pragma unroll
  for (int r = 0; r < 4; ++r) {
    Zc[r].x = __shfl(v[3 - r].x, pidx);
    Zc[r].y = __shfl(v[3 - r].y, pidx);
  }
  float2 z0lane = v[0];
  if (l == 0) { Zc[0] = v[0]; Zc[1] = v[3]; Zc[2] = v[2]; Zc[3] = v[1]; }
  float cl, sl_;
  sincosf(-0.01227184630308513f * (float)l, &sl_, &cl);   // e^{-i pi l/256}
  constexpr float crA[4] = {1.f, 0.7071067811865476f, 0.f, -0.7071067811865476f};
  constexpr float srA[4] = {0.f, -0.7071067811865476f, -1.f, -0.7071067811865476f};
  const float FS = 0.04419417382415922f;                  // 1/sqrt(512)
  #pragma unroll
  for (int r = 0; r < 4; ++r) {
    float Ex = 0.5f * (v[r].x + Zc[r].x), Ey = 0.5f * (v[r].y - Zc[r].y);
    float Dx = v[r].x - Zc[r].x,          Dy = v[r].y + Zc[r].y;
    float Ox = 0.5f * Dy, Oy = -0.5f * Dx;
    float c  = crA[r] * cl - srA[r] * sl_;                // e^{-i pi k/256}
    float sn = crA[r] * sl_ + srA[r] * cl;
    float Wx = (Ex + (c * Ox - sn * Oy)) * FS;
    float Wy = (Ey + (c * Oy + sn * Ox)) * FS;
    int k = 64 * r + l;
    float er = etf_re[k], ei = etf_im[k];
    float Px = Wx * er - Wy * ei;
    float Py = Wx * ei + Wy * er;
    if (k == 0) Py = 0.f;                // irfft drops Im at DC
    row[k] = mkf2(Px, Py);
  }
  if (l == 0) {
    float W256 = (z0lane.x - z0lane.y) * FS;
    row[256] = mkf2(W256 * etf_re[256], 0.f);
  }
}

// ---------------- kernel B: chunked frequency-domain scan, 8-deep pipeline --
struct StepBuf {
  f4a tr, ti;
  float tf256r;
  float4 ia, ib;
  float i256;
};

__device__ inline void loadStep(StepBuf& b, int i, int l,
                                const float* __restrict__ tf_re,
                                const float* __restrict__ tf_im,
                                const float* __restrict__ IMP) {
  const size_t tb = (size_t)i * 257 + 4 * l;
  b.tr = *(const f4a*)(tf_re + tb);
  b.ti = *(const f4a*)(tf_im + tb);
  b.tf256r = tf_re[(size_t)i * 257 + 256];
  const float4* r4 = (const float4*)(IMP + (size_t)(i + 1) * ROWF);
  b.ia = r4[2 * l];
  b.ib = r4[2 * l + 1];
  b.i256 = IMP[(size_t)(i + 1) * ROWF + 512];
}

__device__ inline void doStep(int i, int j0, const StepBuf& b, int l,
                              float2& s0, float2& s1, float2& s2, float2& s3,
                              float& s256, float* __restrict__ S) {
  float2 y0, y1, y2, y3;
  y0.x = s0.x * b.tr[0] - s0.y * b.ti[0];  y0.y = s0.x * b.ti[0] + s0.y * b.tr[0];
  y1.x = s1.x * b.tr[1] - s1.y * b.ti[1];  y1.y = s1.x * b.ti[1] + s1.y * b.tr[1];
  y2.x = s2.x * b.tr[2] - s2.y * b.ti[2];  y2.y = s2.x * b.ti[2] + s2.y * b.tr[2];
  y3.x = s3.x * b.tr[3] - s3.y * b.ti[3];  y3.y = s3.x * b.ti[3] + s3.y * b.tr[3];
  if (l == 0) y0.y = 0.f;              // drop Im at DC (irfft semantics)
  float Y256 = b.tf256r * s256;        // Nyquist, real (Im dropped)
  float phx = __shfl_up(y3.x, 1), phy = __shfl_up(y3.y, 1);
  float nlx = __shfl_down(y0.x, 1), nly = __shfl_down(y0.y, 1);
  float2 p0 = (l == 0)  ? mkf2(y1.x, -y1.y) : mkf2(phx, phy);  // Y_{-1} = conj(Y_1)
  float2 n3 = (l == 63) ? mkf2(Y256, 0.f)   : mkf2(nlx, nly);  // Y_256 (real)
  float y255x = __shfl(y3.x, 63);
  const float A = 0.54f, Bc = 0.23f;
  float2 c0, c1, c2, c3;
  c0.x = A * y0.x - Bc * (p0.x + y1.x);  c0.y = A * y0.y - Bc * (p0.y + y1.y);
  c1.x = A * y1.x - Bc * (y0.x + y2.x);  c1.y = A * y1.y - Bc * (y0.y + y2.y);
  c2.x = A * y2.x - Bc * (y1.x + y3.x);  c2.y = A * y2.y - Bc * (y1.y + y3.y);
  c3.x = A * y3.x - Bc * (y2.x + n3.x);  c3.y = A * y3.y - Bc * (y2.y + n3.y);
  float C256 = A * Y256 - 0.46f * y255x;
  s0.x = c0.x + b.ia.x;  s0.y = c0.y + b.ia.y;
  s1.x = c1.x + b.ia.z;  s1.y = c1.y + b.ia.w;
  s2.x = c2.x + b.ib.x;  s2.y = c2.y + b.ib.y;
  s3.x = c3.x + b.ib.z;  s3.y = c3.y + b.ib.w;
  s256 = C256 + b.i256;
  if (i >= j0) {
    float4* o4 = (float4*)(S + (size_t)(i + 1) * ROWF);
    o4[2 * l]     = make_float4(s0.x, s0.y, s1.x, s1.y);
    o4[2 * l + 1] = make_float4(s2.x, s2.y, s3.x, s3.y);
    if (l == 0) {
      S[(size_t)(i + 1) * ROWF + 512] = s256;
      S[(size_t)(i + 1) * ROWF + 513] = 0.f;
    }
  }
}

__global__ __launch_bounds__(64) void kernB(const float* __restrict__ tf_re,
                                            const float* __restrict__ tf_im,
                                            const float* __restrict__ IMP,
                                            float* __restrict__ S) {
  const int c = blockIdx.x, l = threadIdx.x;
  const int j0 = c * LCH;
  const int jend = min(j0 + LCH, N_STEPS);
  const int w0 = max(0, j0 - KWARM);     // nsteps = 32 (c==0) or 48 -> both %8==0
  const int last = jend - 1;
  float2 s0 = mkf2(0.f, 0.f), s1 = s0, s2 = s0, s3 = s0;
  float s256 = 0.f;
  if (c == 0) {                          // exact init: S_0 = IMP_0; store row 0
    const float4* r4 = (const float4*)IMP;
    float4 a = r4[2 * l], bb = r4[2 * l + 1];
    s0 = mkf2(a.x, a.y);  s1 = mkf2(a.z, a.w);
    s2 = mkf2(bb.x, bb.y); s3 = mkf2(bb.z, bb.w);
    s256 = IMP[512];
    float4* o4 = (float4*)S;
    o4[2 * l] = a; o4[2 * l + 1] = bb;
    if (l == 0) { S[512] = s256; S[513] = 0.f; }
  }
  StepBuf b0, b1, b2, b3, b4, b5, b6, b7;
  loadStep(b0, w0 + 0, l, tf_re, tf_im, IMP);
  loadStep(b1, w0 + 1, l, tf_re, tf_im, IMP);
  loadStep(b2, w0 + 2, l, tf_re, tf_im, IMP);
  loadStep(b3, w0 + 3, l, tf_re, tf_im, IMP);
  loadStep(b4, w0 + 4, l, tf_re, tf_im, IMP);
  loadStep(b5, w0 + 5, l, tf_re, tf_im, IMP);
  loadStep(b6, w0 + 6, l, tf_re, tf_im, IMP);
  loadStep(b7, w0 + 7, l, tf_re, tf_im, IMP);
  int i = w0;
  #define STEP8(BUF) \
    doStep(i, j0, BUF, l, s0, s1, s2, s3, s256, S); \
    { int nx = i + 8; nx = (nx > last) ? last : nx; loadStep(BUF, nx, l, tf_re, tf_im, IMP); } \
    ++i;
  while (i < jend) {
    STEP8(b0) STEP8(b1) STEP8(b2) STEP8(b3)
    STEP8(b4) STEP8(b5) STEP8(b6) STEP8(b7)
  }
  #undef STEP8
}

// ---------------- kernel C: irfft + overlap-add, fused ----------------------
// Block b (9 waves): irfft rows 8b-1 .. 8b+7, exchange halves in LDS,
// write out segments 8b .. 8b+7 directly.
__global__ __launch_bounds__(576) void kernC(const float* __restrict__ S,
                                             float* __restrict__ out) {
  const int l = threadIdx.x & 63;
  const int w = threadIdx.x >> 6;                      // 0..8
  const int b = blockIdx.x;                            // 0..1279
  const int r = 8 * b - 1 + w;                         // -1 .. 10239
  __shared__ float2 ybuf[9][256];
  if (r < 0) {
    #pragma unroll
    for (int rr = 0; rr < 4; ++rr) ybuf[0][64 * rr + l] = mkf2(0.f, 0.f);
  } else {
    const float2* row = (const float2*)(S + (size_t)r * ROWF);
    const float4* r4 = (const float4*)row;
    float4 a = r4[2 * l], bb = r4[2 * l + 1];
    float2 W[4] = {mkf2(a.x, a.y), mkf2(a.z, a.w), mkf2(bb.x, bb.y), mkf2(bb.z, bb.w)};
    float w256 = row[256].x;
    float2 Wm[4];
    const int pidx = (64 - l) & 63;
    Wm[0].x = __shfl(W[0].x, pidx);
    Wm[0].y = __shfl(W[0].y, pidx);
    if (l == 0) Wm[0] = mkf2(w256, 0.f);
    Wm[1].x = __shfl_xor(W[3].x, 63);  Wm[1].y = __shfl_xor(W[3].y, 63);
    Wm[2].x = __shfl_xor(W[2].x, 63);  Wm[2].y = __shfl_xor(W[2].y, 63);
    Wm[3].x = __shfl_xor(W[1].x, 63);  Wm[3].y = __shfl_xor(W[1].y, 63);
    float cl, sl_;
    sincosf(0.04908738521234052f * (float)l, &sl_, &cl);   // e^{+i pi l/64}
    constexpr float crC[4] = {1.f, 0.9999247018391445f, 0.9996988186962042f, 0.9993223845883495f};
    constexpr float srC[4] = {0.f, 0.0122715382857199f, 0.0245412285229123f, 0.0368072229413588f};
    float2 v[4];
    #pragma unroll
    for (int rr = 0; rr < 4; ++rr) {
      float Ex = 0.5f * (W[rr].x + Wm[rr].x), Ey = 0.5f * (W[rr].y - Wm[rr].y);
      float Dx = W[rr].x - Wm[rr].x,          Dy = W[rr].y + Wm[rr].y;
      float c  = cl * crC[rr] - sl_ * srC[rr];
      float sn = cl * srC[rr] + sl_ * crC[rr];
      float Ox = 0.5f * (c * Dx - sn * Dy);
      float Oy = 0.5f * (c * Dy + sn * Dx);
      v[rr] = mkf2(Ex - Oy, Ey + Ox);
    }
    waveFFT256<+1>(v, l);                  // v[k1] = z[64*k1 + l]
    const float ISC = 0.08838834764831845f;  // sqrt(512)/256
    #pragma unroll
    for (int rr = 0; rr < 4; ++rr)
      ybuf[w][64 * rr + l] = mkf2(v[rr].x * ISC, v[rr].y * ISC);
  }
  __syncthreads();
  // OA: out2[(8b+k)*128 + t2] = y_{8b+k}[t2] + y_{8b+k-1}[128+t2]
  float2* out2 = (float2*)out;
  const size_t base = (size_t)b * 1024;
  for (int idx = threadIdx.x; idx < 1024; idx += 576) {
    const int k = idx >> 7, t2 = idx & 127;
    float2 a = ybuf[k + 1][t2];
    float2 p = ybuf[k][128 + t2];
    out2[base + idx] = mkf2(a.x + p.x, a.y + p.y);
  }
}

// ---------------- launch ----------------
extern "C" void kernel_launch(void* const* d_in, const int* in_sizes, int n_in,
                              void* d_out, int out_size, void* d_ws, size_t ws_size,
                              hipStream_t stream) {
  const float* env    = (const float*)d_in[1];
  const float* tf_re  = (const float*)d_in[2];
  const float* tf_im  = (const float*)d_in[3];
  const float* etf_re = (const float*)d_in[4];
  const float* etf_im = (const float*)d_in[5];
  const float* noise  = (const float*)d_in[6];
  float* out = (float*)d_out;

  float* wsf = (float*)d_ws;
  float* IMP = wsf;                                    // (N_STEPS+1) x ROWF
  float* S   = wsf + (size_t)(N_STEPS + 1) * ROWF;     // (N_STEPS+1) x ROWF
  // ws use: 2 * 10241 * 528 * 4 B ~= 43.3 MB

  kernA<<<(N_STEPS / 4) + 1, 256, 0, stream>>>(env, noise, etf_re, etf_im, IMP);
  kernB<<<N_STEPS / LCH, 64, 0, stream>>>(tf_re, tf_im, IMP, S);
  kernC<<<N_STEPS / 8, 576, 0, stream>>>(S, out);
}